// Round 5
// baseline (488.372 us; speedup 1.0000x reference)
//
#include <hip/hip_runtime.h>

// ---------------------------------------------------------------------------
// ROIAwareGCN: 3x GCNConv + mean-pool + MLP.
// R1: atomic pool -> segmented reduction over sorted batch.
// R2: split-bf16 MFMA GEMM (no LDS), bf16 t, gather ILP.
// R3: padded CSR (int4/float4, dummy wgt=0), bf16 h, fused preproc. 20->13 nodes.
// R4: 13->11 nodes (pool+mlp fused; col/wgt memset replaced by explicit pad-fill
//     in k_csr tail; wpack W1 into k_pre tail); k_scan 2-phase thread-serial
//     (2 barriers vs 52); agg 16-deep gather burst; h3 bf16.
// ---------------------------------------------------------------------------

typedef __bf16 bf16x8 __attribute__((ext_vector_type(8)));
typedef float f32x4 __attribute__((ext_vector_type(4)));

__device__ __forceinline__ float bflo(unsigned u) { return __uint_as_float(u << 16); }
__device__ __forceinline__ float bfhi(unsigned u) { return __uint_as_float(u & 0xffff0000u); }

union BF2 {
    __bf16 h[2];
    unsigned u;
};

// ---------------- W pre-pack into MFMA B-fragment layout ----------------
__device__ __forceinline__ void wpack_block(const float* __restrict__ W,
                                            __bf16* __restrict__ hi,
                                            __bf16* __restrict__ lo, int N, int b, int l) {
    int t = b >> 2, c = b & 3;
    int k0 = c * 32 + (l >> 4) * 8;
    int ncol = t * 16 + (l & 15);
    size_t base = ((size_t)b * 64 + l) * 8;
#pragma unroll
    for (int j = 0; j < 8; j++) {
        float v = W[(size_t)(k0 + j) * N + ncol];
        __bf16 h = (__bf16)v;
        hi[base + j] = h;
        lo[base + j] = (__bf16)(v - (float)h);
    }
}

// ---------------- fused: degree count + graph boundaries + wpack(W1) ----------------
__global__ void k_pre(const int* __restrict__ dst, int* __restrict__ cnt,
                      const int* __restrict__ batch, int* __restrict__ gstart,
                      const float* __restrict__ W1, __bf16* __restrict__ Wp1h,
                      __bf16* __restrict__ Wp1l, int E, int n, int G, int EB) {
    int b = blockIdx.x;
    if (b < EB) {
        int e = b * 256 + threadIdx.x;
        if (e < E) atomicAdd(&cnt[dst[e]], 1);
    } else if (b == EB) {
        int g = threadIdx.x;
        if (g <= G) {
            int lo = 0, hi = n;
            while (lo < hi) {
                int mid = (lo + hi) >> 1;
                if (batch[mid] < g) lo = mid + 1; else hi = mid;
            }
            gstart[g] = lo;  // lower_bound: first i with batch[i] >= g
        }
    } else {
        int b64 = (b - EB - 1) * 4 + (threadIdx.x >> 6);  // 0..31
        if (b64 < 32) wpack_block(W1, Wp1h, Wp1l, 128, b64, threadIdx.x & 63);
    }
}

// ---------------- scan (2-phase, thread-serial chunks) -> rowptr, dinv, fill2 ----------
// rowptr over PADDED counts ((c+3)&~3); fill2 = copy of rowptr used as scatter cursor.
__global__ __launch_bounds__(1024) void k_scan(const int* __restrict__ cnt,
                                               int* __restrict__ rowptr,
                                               int* __restrict__ fill2,
                                               float* __restrict__ dinv, int n) {
    __shared__ int wsum[16];
    int tid = threadIdx.x;
    int lane = tid & 63;
    int wid = tid >> 6;
    int per = (n + 1023) / 1024;
    int i0 = tid * per;
    int i1 = i0 + per;
    if (i1 > n) i1 = n;
    int s = 0;
    for (int i = i0; i < i1; i++) {
        int c = cnt[i];
        dinv[i] = rsqrtf((float)(c + 1));
        s += (c + 3) & ~3;
    }
    int sc = s;
#pragma unroll
    for (int d = 1; d < 64; d <<= 1) {
        int o = __shfl_up(sc, d);
        if (lane >= d) sc += o;
    }
    if (lane == 63) wsum[wid] = sc;
    __syncthreads();
    if (wid == 0) {
        int v = (lane < 16) ? wsum[lane] : 0;
        int sc2 = v;
#pragma unroll
        for (int d = 1; d < 16; d <<= 1) {
            int o = __shfl_up(sc2, d);
            if (lane >= d) sc2 += o;
        }
        if (lane < 16) wsum[lane] = sc2;
    }
    __syncthreads();
    int off = ((wid > 0) ? wsum[wid - 1] : 0) + (sc - s);
    for (int i = i0; i < i1; i++) {
        rowptr[i] = off;
        fill2[i] = off;
        off += (cnt[i] + 3) & ~3;
    }
    if (tid == 1023) rowptr[n] = off;
}

// ---------------- CSR scatter + wpack(W2,W3) + padding fill ----------------
__global__ void k_csr(const int* __restrict__ src, const int* __restrict__ dst,
                      const int* __restrict__ rowptr, int* __restrict__ fill2,
                      const int* __restrict__ cnt,
                      const float* __restrict__ dinv, int* __restrict__ col,
                      float* __restrict__ wgt, int E, int EB, int n,
                      const float* __restrict__ W2, const float* __restrict__ W3,
                      __bf16* __restrict__ Wp2h, __bf16* __restrict__ Wp2l,
                      __bf16* __restrict__ Wp3h, __bf16* __restrict__ Wp3l) {
    int b = blockIdx.x;
    if (b < EB) {
        int e = b * 256 + threadIdx.x;
        if (e >= E) return;
        int s = src[e], d = dst[e];
        int pos = atomicAdd(&fill2[d], 1);
        col[pos] = s;
        wgt[pos] = dinv[s] * dinv[d];
        return;
    }
    int idx = b - EB;
    if (idx < 12) {  // weight packing: 48 wave-blocks
        int b64 = idx * 4 + (threadIdx.x >> 6);
        int l = threadIdx.x & 63;
        if (b64 < 32) wpack_block(W2, Wp2h, Wp2l, 128, b64, l);
        else if (b64 < 48) wpack_block(W3, Wp3h, Wp3l, 64, b64 - 32, l);
        return;
    }
    // padding slots: [rowptr[w] + deg(w), rowptr[w+1]) -> col=0, wgt=0
    int w = (idx - 12) * 256 + threadIdx.x;
    if (w >= n) return;
    int p = rowptr[w] + cnt[w];
    int pe = rowptr[w + 1];
    for (; p < pe; p++) {
        col[p] = 0;
        wgt[p] = 0.f;
    }
}

// ---------------- MFMA GEMMs ----------------
// fp32 A (layer 1): hi/lo split, 3 mfma per K-chunk.
template <int NT>
__global__ __launch_bounds__(256) void k_gemm_f32(const float* __restrict__ A,
                                                  const __bf16* __restrict__ Wp_hi,
                                                  const __bf16* __restrict__ Wp_lo,
                                                  __bf16* __restrict__ Cbf, int n) {
    constexpr int N = NT * 16;
    int wave = (int)((blockIdx.x * 256u + threadIdx.x) >> 6);
    int lane = threadIdx.x & 63;
    int row0 = wave * 16;
    if (row0 >= n) return;
    int m = lane & 15;
    int q = lane >> 4;
    int row = row0 + m;
    if (row >= n) row = n - 1;
    const float* ap = A + (size_t)row * 128 + q * 8;
    bf16x8 ahi[4], alo[4];
#pragma unroll
    for (int c = 0; c < 4; c++) {
        float4 v0 = *(const float4*)(ap + c * 32);
        float4 v1 = *(const float4*)(ap + c * 32 + 4);
        float vv[8] = {v0.x, v0.y, v0.z, v0.w, v1.x, v1.y, v1.z, v1.w};
#pragma unroll
        for (int j = 0; j < 8; j++) {
            __bf16 h = (__bf16)vv[j];
            ahi[c][j] = h;
            alo[c][j] = (__bf16)(vv[j] - (float)h);
        }
    }
#pragma unroll
    for (int t = 0; t < NT; t++) {
        f32x4 acc = {0.f, 0.f, 0.f, 0.f};
#pragma unroll
        for (int c = 0; c < 4; c++) {
            size_t off = ((size_t)(t * 4 + c) * 64 + lane) * 8;
            bf16x8 bh = *(const bf16x8*)(Wp_hi + off);
            bf16x8 bl = *(const bf16x8*)(Wp_lo + off);
            acc = __builtin_amdgcn_mfma_f32_16x16x32_bf16(ahi[c], bh, acc, 0, 0, 0);
            acc = __builtin_amdgcn_mfma_f32_16x16x32_bf16(alo[c], bh, acc, 0, 0, 0);
            acc = __builtin_amdgcn_mfma_f32_16x16x32_bf16(ahi[c], bl, acc, 0, 0, 0);
        }
        int colx = t * 16 + m;
#pragma unroll
        for (int r = 0; r < 4; r++) {
            int orow = row0 + q * 4 + r;
            if (orow < n) Cbf[(size_t)orow * N + colx] = (__bf16)acc[r];
        }
    }
}

// bf16 A (layers 2/3): 2 mfma per K-chunk.
template <int NT>
__global__ __launch_bounds__(256) void k_gemm_bf16(const __bf16* __restrict__ A,
                                                   const __bf16* __restrict__ Wp_hi,
                                                   const __bf16* __restrict__ Wp_lo,
                                                   __bf16* __restrict__ Cbf, int n) {
    constexpr int N = NT * 16;
    int wave = (int)((blockIdx.x * 256u + threadIdx.x) >> 6);
    int lane = threadIdx.x & 63;
    int row0 = wave * 16;
    if (row0 >= n) return;
    int m = lane & 15;
    int q = lane >> 4;
    int row = row0 + m;
    if (row >= n) row = n - 1;
    const __bf16* ap = A + (size_t)row * 128 + q * 8;
    bf16x8 a[4];
#pragma unroll
    for (int c = 0; c < 4; c++) a[c] = *(const bf16x8*)(ap + c * 32);
#pragma unroll
    for (int t = 0; t < NT; t++) {
        f32x4 acc = {0.f, 0.f, 0.f, 0.f};
#pragma unroll
        for (int c = 0; c < 4; c++) {
            size_t off = ((size_t)(t * 4 + c) * 64 + lane) * 8;
            bf16x8 bh = *(const bf16x8*)(Wp_hi + off);
            bf16x8 bl = *(const bf16x8*)(Wp_lo + off);
            acc = __builtin_amdgcn_mfma_f32_16x16x32_bf16(a[c], bh, acc, 0, 0, 0);
            acc = __builtin_amdgcn_mfma_f32_16x16x32_bf16(a[c], bl, acc, 0, 0, 0);
        }
        int colx = t * 16 + m;
#pragma unroll
        for (int r = 0; r < 4; r++) {
            int orow = row0 + q * 4 + r;
            if (orow < n) Cbf[(size_t)orow * N + colx] = (__bf16)acc[r];
        }
    }
}

// ---------------- aggregation (padded CSR, 16/8/4-deep gather bursts) ----------------
#define AGG128_BODY(CVEC, WVEC, OFS)                                   \
    {                                                                  \
        unsigned u0 = t32[((size_t)CVEC.x << 6) + lane];               \
        unsigned u1 = t32[((size_t)CVEC.y << 6) + lane];               \
        unsigned u2 = t32[((size_t)CVEC.z << 6) + lane];               \
        unsigned u3 = t32[((size_t)CVEC.w << 6) + lane];               \
        a0 += WVEC.x * bflo(u0); a1 += WVEC.x * bfhi(u0);              \
        a0 += WVEC.y * bflo(u1); a1 += WVEC.y * bfhi(u1);              \
        a0 += WVEC.z * bflo(u2); a1 += WVEC.z * bfhi(u2);              \
        a0 += WVEC.w * bflo(u3); a1 += WVEC.w * bfhi(u3);              \
    }

__global__ __launch_bounds__(256) void k_agg128(const unsigned int* __restrict__ t32,
                                                const int* __restrict__ rowptr,
                                                const int* __restrict__ col,
                                                const float* __restrict__ wgt,
                                                const float* __restrict__ dinv,
                                                const float* __restrict__ bias,
                                                unsigned int* __restrict__ out, int n) {
    int w = (int)((blockIdx.x * 256u + threadIdx.x) >> 6);
    int lane = threadIdx.x & 63;
    if (w >= n) return;
    float di = dinv[w];
    float sw = di * di;
    unsigned us = t32[(size_t)w * 64 + lane];
    float a0 = sw * bflo(us);
    float a1 = sw * bfhi(us);
    int p = rowptr[w], pe = rowptr[w + 1];
    for (; p + 16 <= pe; p += 16) {  // 16 gathers in flight
        int4 c0 = *(const int4*)(col + p);
        int4 c1 = *(const int4*)(col + p + 4);
        int4 c2 = *(const int4*)(col + p + 8);
        int4 c3 = *(const int4*)(col + p + 12);
        float4 w0 = *(const float4*)(wgt + p);
        float4 w1 = *(const float4*)(wgt + p + 4);
        float4 w2 = *(const float4*)(wgt + p + 8);
        float4 w3 = *(const float4*)(wgt + p + 12);
        unsigned u0 = t32[((size_t)c0.x << 6) + lane];
        unsigned u1 = t32[((size_t)c0.y << 6) + lane];
        unsigned u2 = t32[((size_t)c0.z << 6) + lane];
        unsigned u3 = t32[((size_t)c0.w << 6) + lane];
        unsigned u4 = t32[((size_t)c1.x << 6) + lane];
        unsigned u5 = t32[((size_t)c1.y << 6) + lane];
        unsigned u6 = t32[((size_t)c1.z << 6) + lane];
        unsigned u7 = t32[((size_t)c1.w << 6) + lane];
        unsigned u8 = t32[((size_t)c2.x << 6) + lane];
        unsigned u9 = t32[((size_t)c2.y << 6) + lane];
        unsigned ua = t32[((size_t)c2.z << 6) + lane];
        unsigned ub = t32[((size_t)c2.w << 6) + lane];
        unsigned uc = t32[((size_t)c3.x << 6) + lane];
        unsigned ud = t32[((size_t)c3.y << 6) + lane];
        unsigned ue = t32[((size_t)c3.z << 6) + lane];
        unsigned uf = t32[((size_t)c3.w << 6) + lane];
        a0 += w0.x * bflo(u0); a1 += w0.x * bfhi(u0);
        a0 += w0.y * bflo(u1); a1 += w0.y * bfhi(u1);
        a0 += w0.z * bflo(u2); a1 += w0.z * bfhi(u2);
        a0 += w0.w * bflo(u3); a1 += w0.w * bfhi(u3);
        a0 += w1.x * bflo(u4); a1 += w1.x * bfhi(u4);
        a0 += w1.y * bflo(u5); a1 += w1.y * bfhi(u5);
        a0 += w1.z * bflo(u6); a1 += w1.z * bfhi(u6);
        a0 += w1.w * bflo(u7); a1 += w1.w * bfhi(u7);
        a0 += w2.x * bflo(u8); a1 += w2.x * bfhi(u8);
        a0 += w2.y * bflo(u9); a1 += w2.y * bfhi(u9);
        a0 += w2.z * bflo(ua); a1 += w2.z * bfhi(ua);
        a0 += w2.w * bflo(ub); a1 += w2.w * bfhi(ub);
        a0 += w3.x * bflo(uc); a1 += w3.x * bfhi(uc);
        a0 += w3.y * bflo(ud); a1 += w3.y * bfhi(ud);
        a0 += w3.z * bflo(ue); a1 += w3.z * bfhi(ue);
        a0 += w3.w * bflo(uf); a1 += w3.w * bfhi(uf);
    }
    for (; p + 8 <= pe; p += 8) {
        int4 c0 = *(const int4*)(col + p);
        int4 c1 = *(const int4*)(col + p + 4);
        float4 w0 = *(const float4*)(wgt + p);
        float4 w1 = *(const float4*)(wgt + p + 4);
        AGG128_BODY(c0, w0, 0)
        AGG128_BODY(c1, w1, 4)
    }
    if (p < pe) {
        int4 c0 = *(const int4*)(col + p);
        float4 w0 = *(const float4*)(wgt + p);
        AGG128_BODY(c0, w0, 0)
    }
    BF2 o;
    o.h[0] = (__bf16)fmaxf(a0 + bias[lane * 2], 0.f);
    o.h[1] = (__bf16)fmaxf(a1 + bias[lane * 2 + 1], 0.f);
    out[(size_t)w * 64 + lane] = o.u;
}

__global__ __launch_bounds__(256) void k_agg64(const unsigned short* __restrict__ t16,
                                               const int* __restrict__ rowptr,
                                               const int* __restrict__ col,
                                               const float* __restrict__ wgt,
                                               const float* __restrict__ dinv,
                                               const float* __restrict__ bias,
                                               __bf16* __restrict__ out, int n) {
    int w = (int)((blockIdx.x * 256u + threadIdx.x) >> 6);
    int lane = threadIdx.x & 63;
    if (w >= n) return;
    float di = dinv[w];
    float sw = di * di;
    float acc = sw * __uint_as_float((unsigned)t16[(size_t)w * 64 + lane] << 16);
    int p = rowptr[w], pe = rowptr[w + 1];
    for (; p + 16 <= pe; p += 16) {
        int4 c0 = *(const int4*)(col + p);
        int4 c1 = *(const int4*)(col + p + 4);
        int4 c2 = *(const int4*)(col + p + 8);
        int4 c3 = *(const int4*)(col + p + 12);
        float4 w0 = *(const float4*)(wgt + p);
        float4 w1 = *(const float4*)(wgt + p + 4);
        float4 w2 = *(const float4*)(wgt + p + 8);
        float4 w3 = *(const float4*)(wgt + p + 12);
        unsigned u0 = t16[((size_t)c0.x << 6) + lane];
        unsigned u1 = t16[((size_t)c0.y << 6) + lane];
        unsigned u2 = t16[((size_t)c0.z << 6) + lane];
        unsigned u3 = t16[((size_t)c0.w << 6) + lane];
        unsigned u4 = t16[((size_t)c1.x << 6) + lane];
        unsigned u5 = t16[((size_t)c1.y << 6) + lane];
        unsigned u6 = t16[((size_t)c1.z << 6) + lane];
        unsigned u7 = t16[((size_t)c1.w << 6) + lane];
        unsigned u8 = t16[((size_t)c2.x << 6) + lane];
        unsigned u9 = t16[((size_t)c2.y << 6) + lane];
        unsigned ua = t16[((size_t)c2.z << 6) + lane];
        unsigned ub = t16[((size_t)c2.w << 6) + lane];
        unsigned uc = t16[((size_t)c3.x << 6) + lane];
        unsigned ud = t16[((size_t)c3.y << 6) + lane];
        unsigned ue = t16[((size_t)c3.z << 6) + lane];
        unsigned uf = t16[((size_t)c3.w << 6) + lane];
        acc += w0.x * __uint_as_float(u0 << 16);
        acc += w0.y * __uint_as_float(u1 << 16);
        acc += w0.z * __uint_as_float(u2 << 16);
        acc += w0.w * __uint_as_float(u3 << 16);
        acc += w1.x * __uint_as_float(u4 << 16);
        acc += w1.y * __uint_as_float(u5 << 16);
        acc += w1.z * __uint_as_float(u6 << 16);
        acc += w1.w * __uint_as_float(u7 << 16);
        acc += w2.x * __uint_as_float(u8 << 16);
        acc += w2.y * __uint_as_float(u9 << 16);
        acc += w2.z * __uint_as_float(ua << 16);
        acc += w2.w * __uint_as_float(ub << 16);
        acc += w3.x * __uint_as_float(uc << 16);
        acc += w3.y * __uint_as_float(ud << 16);
        acc += w3.z * __uint_as_float(ue << 16);
        acc += w3.w * __uint_as_float(uf << 16);
    }
    for (; p + 4 <= pe; p += 4) {
        int4 c0 = *(const int4*)(col + p);
        float4 w0 = *(const float4*)(wgt + p);
        unsigned u0 = t16[((size_t)c0.x << 6) + lane];
        unsigned u1 = t16[((size_t)c0.y << 6) + lane];
        unsigned u2 = t16[((size_t)c0.z << 6) + lane];
        unsigned u3 = t16[((size_t)c0.w << 6) + lane];
        acc += w0.x * __uint_as_float(u0 << 16);
        acc += w0.y * __uint_as_float(u1 << 16);
        acc += w0.z * __uint_as_float(u2 << 16);
        acc += w0.w * __uint_as_float(u3 << 16);
    }
    out[(size_t)w * 64 + lane] = (__bf16)fmaxf(acc + bias[lane], 0.f);
}

// ---------------- fused mean-pool + MLP head ----------------
__global__ __launch_bounds__(256) void k_poolmlp(const unsigned short* __restrict__ h,
                                                 const int* __restrict__ gstart,
                                                 const float* __restrict__ demo,
                                                 const float* __restrict__ Wf1,
                                                 const float* __restrict__ bf1,
                                                 const float* __restrict__ Wf2,
                                                 const float* __restrict__ bf2,
                                                 const float* __restrict__ Wf3,
                                                 const float* __restrict__ bf3,
                                                 float* __restrict__ out, int G) {
    int g = blockIdx.x;
    int tid = threadIdx.x;
    int lane = tid & 63;
    int wv = tid >> 6;
    int s = gstart[g], e = gstart[g + 1];
    float acc = 0.f;
    for (int i = s + wv; i < e; i += 4)
        acc += __uint_as_float((unsigned)h[(size_t)i * 64 + lane] << 16);
    __shared__ float red[4][64];
    __shared__ float zin[72];
    __shared__ float z1[64];
    __shared__ float z2[32];
    red[wv][lane] = acc;
    if (tid >= 64 && tid < 72) zin[tid] = demo[g * 8 + (tid - 64)];
    __syncthreads();
    if (tid < 64) {
        float v = red[0][tid] + red[1][tid] + red[2][tid] + red[3][tid];
        zin[tid] = v / fmaxf((float)(e - s), 1.0f);
    }
    __syncthreads();
    if (tid < 64) {
        float a = bf1[tid];
        for (int k = 0; k < 72; k++) a += zin[k] * Wf1[k * 64 + tid];
        z1[tid] = fmaxf(a, 0.f);
    }
    __syncthreads();
    if (tid < 32) {
        float a2 = bf2[tid];
        for (int k = 0; k < 64; k++) a2 += z1[k] * Wf2[k * 32 + tid];
        z2[tid] = fmaxf(a2, 0.f);
    }
    __syncthreads();
    if (tid < 2) {
        float a3 = bf3[tid];
        for (int k = 0; k < 32; k++) a3 += z2[k] * Wf3[k * 2 + tid];
        out[g * 2 + tid] = a3;
    }
}

extern "C" void kernel_launch(void* const* d_in, const int* in_sizes, int n_in,
                              void* d_out, int out_size, void* d_ws, size_t ws_size,
                              hipStream_t stream) {
    const float* x    = (const float*)d_in[0];
    const int*   ei   = (const int*)d_in[1];
    const int*   batch= (const int*)d_in[2];
    const float* demo = (const float*)d_in[3];
    const float* W1   = (const float*)d_in[4];
    const float* b1   = (const float*)d_in[5];
    const float* W2   = (const float*)d_in[6];
    const float* b2   = (const float*)d_in[7];
    const float* W3   = (const float*)d_in[8];
    const float* b3   = (const float*)d_in[9];
    const float* Wf1  = (const float*)d_in[10];
    const float* bf1  = (const float*)d_in[11];
    const float* Wf2  = (const float*)d_in[12];
    const float* bf2  = (const float*)d_in[13];
    const float* Wf3  = (const float*)d_in[14];
    const float* bf3  = (const float*)d_in[15];
    float* out = (float*)d_out;

    const int n = in_sizes[0] / 128;  // 50000
    const int E = in_sizes[1] / 2;    // 600000
    const int G = in_sizes[3] / 8;    // 100
    const int Epad = E + 3 * n;       // worst-case padded CSR size

    char* ws = (char*)d_ws;
    auto alloc = [&](size_t bytes) {
        char* p = ws;
        ws += (bytes + 255) & ~(size_t)255;
        return p;
    };
    int*    cnt    = (int*)alloc((size_t)n * 4);
    float*  dinv   = (float*)alloc((size_t)n * 4);
    int*    rowptr = (int*)alloc((size_t)(n + 1) * 4);
    int*    fill2  = (int*)alloc((size_t)n * 4);   // scatter cursor (copy of rowptr)
    int*    col    = (int*)alloc((size_t)Epad * 4);
    float*  wgt    = (float*)alloc((size_t)Epad * 4);
    __bf16* tbf    = (__bf16*)alloc((size_t)n * 128 * 2);  // GEMM out bf16 (layers 1/2)
    __bf16* hbuf   = (__bf16*)alloc((size_t)n * 128 * 2);  // agg out bf16
    __bf16* t3bf   = (__bf16*)alloc((size_t)n * 64 * 2);   // GEMM3 out
    __bf16* h3     = (__bf16*)alloc((size_t)n * 64 * 2);   // agg3 out (bf16)
    __bf16* Wp1h   = (__bf16*)alloc(128 * 128 * 2);
    __bf16* Wp1l   = (__bf16*)alloc(128 * 128 * 2);
    __bf16* Wp2h   = (__bf16*)alloc(128 * 128 * 2);
    __bf16* Wp2l   = (__bf16*)alloc(128 * 128 * 2);
    __bf16* Wp3h   = (__bf16*)alloc(128 * 64 * 2);
    __bf16* Wp3l   = (__bf16*)alloc(128 * 64 * 2);
    int*    gstart = (int*)alloc((size_t)(G + 1) * 4);

    const int* srcv = ei;
    const int* dstv = ei + E;

    hipMemsetAsync(cnt, 0, (size_t)n * 4, stream);

    const int EB = (E + 255) / 256;
    const int NB = (n + 255) / 256;
    // k_pre: EB degree blocks + 1 gstart block + 8 wpack(W1) blocks
    k_pre<<<EB + 9, 256, 0, stream>>>(dstv, cnt, batch, gstart, W1, Wp1h, Wp1l, E, n, G, EB);
    k_scan<<<1, 1024, 0, stream>>>(cnt, rowptr, fill2, dinv, n);
    // k_csr: EB scatter blocks + 12 wpack(W2,W3) blocks + NB padding-fill blocks
    k_csr<<<EB + 12 + NB, 256, 0, stream>>>(srcv, dstv, rowptr, fill2, cnt, dinv, col, wgt,
                                            E, EB, n, W2, W3, Wp2h, Wp2l, Wp3h, Wp3l);

    int waves = (n + 15) / 16;
    int gemm_blocks = (waves + 3) / 4;
    int agg_blocks = (int)(((size_t)n * 64 + 255) / 256);

    // Layer 1
    k_gemm_f32<8><<<gemm_blocks, 256, 0, stream>>>(x, Wp1h, Wp1l, tbf, n);
    k_agg128<<<agg_blocks, 256, 0, stream>>>((const unsigned int*)tbf, rowptr, col, wgt,
                                             dinv, b1, (unsigned int*)hbuf, n);
    // Layer 2
    k_gemm_bf16<8><<<gemm_blocks, 256, 0, stream>>>(hbuf, Wp2h, Wp2l, tbf, n);
    k_agg128<<<agg_blocks, 256, 0, stream>>>((const unsigned int*)tbf, rowptr, col, wgt,
                                             dinv, b2, (unsigned int*)hbuf, n);
    // Layer 3 (128 -> 64)
    k_gemm_bf16<4><<<gemm_blocks, 256, 0, stream>>>(hbuf, Wp3h, Wp3l, t3bf, n);
    k_agg64<<<agg_blocks, 256, 0, stream>>>((const unsigned short*)t3bf, rowptr, col, wgt,
                                            dinv, b3, h3, n);

    k_poolmlp<<<G, 256, 0, stream>>>((const unsigned short*)h3, gstart, demo,
                                     Wf1, bf1, Wf2, bf2, Wf3, bf3, out, G);
}

// Round 6
// 371.866 us; speedup vs baseline: 1.3133x; 1.3133x over previous
//
#include <hip/hip_runtime.h>

// ---------------------------------------------------------------------------
// ROIAwareGCN: 3x GCNConv + mean-pool + MLP.
// R1: atomic pool -> segmented reduction over sorted batch.
// R2: split-bf16 MFMA GEMM (no LDS), bf16 t, gather ILP.
// R3: padded CSR (int4/float4, dummy wgt=0), bf16 h, fused preproc.
// R4: pool+mlp fused; pad-fill instead of col/wgt memset; 16-deep agg bursts;
//     h3 bf16. (k_scan thread-serial rewrite REGRESSED 165us: uncoalesced.)
// R5: k_scan reverted to coalesced chunked scan (dwordx4/lane, shuffle scan,
//     ~13 chunks x 4 barriers) -- on a single-block kernel coalescing >>
//     barrier count. Everything else kept from R4.
// ---------------------------------------------------------------------------

typedef __bf16 bf16x8 __attribute__((ext_vector_type(8)));
typedef float f32x4 __attribute__((ext_vector_type(4)));

__device__ __forceinline__ float bflo(unsigned u) { return __uint_as_float(u << 16); }
__device__ __forceinline__ float bfhi(unsigned u) { return __uint_as_float(u & 0xffff0000u); }

union BF2 {
    __bf16 h[2];
    unsigned u;
};

// ---------------- W pre-pack into MFMA B-fragment layout ----------------
__device__ __forceinline__ void wpack_block(const float* __restrict__ W,
                                            __bf16* __restrict__ hi,
                                            __bf16* __restrict__ lo, int N, int b, int l) {
    int t = b >> 2, c = b & 3;
    int k0 = c * 32 + (l >> 4) * 8;
    int ncol = t * 16 + (l & 15);
    size_t base = ((size_t)b * 64 + l) * 8;
#pragma unroll
    for (int j = 0; j < 8; j++) {
        float v = W[(size_t)(k0 + j) * N + ncol];
        __bf16 h = (__bf16)v;
        hi[base + j] = h;
        lo[base + j] = (__bf16)(v - (float)h);
    }
}

// ---------------- fused: degree count + graph boundaries + wpack(W1) ----------------
__global__ void k_pre(const int* __restrict__ dst, int* __restrict__ cnt,
                      const int* __restrict__ batch, int* __restrict__ gstart,
                      const float* __restrict__ W1, __bf16* __restrict__ Wp1h,
                      __bf16* __restrict__ Wp1l, int E, int n, int G, int EB) {
    int b = blockIdx.x;
    if (b < EB) {
        int e = b * 256 + threadIdx.x;
        if (e < E) atomicAdd(&cnt[dst[e]], 1);
    } else if (b == EB) {
        int g = threadIdx.x;
        if (g <= G) {
            int lo = 0, hi = n;
            while (lo < hi) {
                int mid = (lo + hi) >> 1;
                if (batch[mid] < g) lo = mid + 1; else hi = mid;
            }
            gstart[g] = lo;  // lower_bound: first i with batch[i] >= g
        }
    } else {
        int b64 = (b - EB - 1) * 4 + (threadIdx.x >> 6);  // 0..31
        if (b64 < 32) wpack_block(W1, Wp1h, Wp1l, 128, b64, threadIdx.x & 63);
    }
}

// ---------------- coalesced chunked scan -> rowptr, fill2, dinv ----------------
// rowptr over PADDED counts ((c+3)&~3); fill2 = copy of rowptr (scatter cursor).
// Each lane: one dwordx4 per chunk (lanes adjacent 16B) -- fully coalesced.
__global__ __launch_bounds__(1024) void k_scan(const int* __restrict__ cnt,
                                               int* __restrict__ rowptr,
                                               int* __restrict__ fill2,
                                               float* __restrict__ dinv, int n) {
    __shared__ int wsum[16];
    __shared__ int carry_s;
    int tid = threadIdx.x;
    int lane = tid & 63;
    int wid = tid >> 6;
    if (tid == 0) carry_s = 0;
    __syncthreads();
    for (int base = 0; base < n; base += 4096) {
        int i0 = base + tid * 4;
        int v[4], pv[4];
#pragma unroll
        for (int j = 0; j < 4; j++) {
            v[j] = (i0 + j < n) ? cnt[i0 + j] : 0;
            pv[j] = (v[j] + 3) & ~3;  // pad row to multiple of 4
            if (i0 + j < n) dinv[i0 + j] = rsqrtf((float)(v[j] + 1));
        }
        int s0 = pv[0], s1 = s0 + pv[1], s2 = s1 + pv[2], s3 = s2 + pv[3];
        int ts = s3;
        int sc = ts;
#pragma unroll
        for (int d = 1; d < 64; d <<= 1) {
            int o = __shfl_up(sc, d);
            if (lane >= d) sc += o;
        }
        if (lane == 63) wsum[wid] = sc;
        __syncthreads();
        if (wid == 0) {
            int v2 = (lane < 16) ? wsum[lane] : 0;
            int sc2 = v2;
#pragma unroll
            for (int d = 1; d < 16; d <<= 1) {
                int o = __shfl_up(sc2, d);
                if (lane >= d) sc2 += o;
            }
            if (lane < 16) wsum[lane] = sc2;
        }
        __syncthreads();
        int waveoff = (wid > 0) ? wsum[wid - 1] : 0;
        int throff = carry_s + waveoff + (sc - ts);
#pragma unroll
        for (int j = 0; j < 4; j++) {
            int idx = i0 + j;
            int pre = (j == 0) ? 0 : (j == 1 ? s0 : (j == 2 ? s1 : s2));
            if (idx < n) {
                int o = throff + pre;
                rowptr[idx] = o;
                fill2[idx] = o;
            }
        }
        __syncthreads();
        if (tid == 0) carry_s += wsum[15];
        __syncthreads();
    }
    if (threadIdx.x == 0) rowptr[n] = carry_s;
}

// ---------------- CSR scatter + wpack(W2,W3) + padding fill ----------------
__global__ void k_csr(const int* __restrict__ src, const int* __restrict__ dst,
                      const int* __restrict__ rowptr, int* __restrict__ fill2,
                      const int* __restrict__ cnt,
                      const float* __restrict__ dinv, int* __restrict__ col,
                      float* __restrict__ wgt, int E, int EB, int n,
                      const float* __restrict__ W2, const float* __restrict__ W3,
                      __bf16* __restrict__ Wp2h, __bf16* __restrict__ Wp2l,
                      __bf16* __restrict__ Wp3h, __bf16* __restrict__ Wp3l) {
    int b = blockIdx.x;
    if (b < EB) {
        int e = b * 256 + threadIdx.x;
        if (e >= E) return;
        int s = src[e], d = dst[e];
        int pos = atomicAdd(&fill2[d], 1);
        col[pos] = s;
        wgt[pos] = dinv[s] * dinv[d];
        return;
    }
    int idx = b - EB;
    if (idx < 12) {  // weight packing: 48 wave-blocks
        int b64 = idx * 4 + (threadIdx.x >> 6);
        int l = threadIdx.x & 63;
        if (b64 < 32) wpack_block(W2, Wp2h, Wp2l, 128, b64, l);
        else if (b64 < 48) wpack_block(W3, Wp3h, Wp3l, 64, b64 - 32, l);
        return;
    }
    // padding slots: [rowptr[w] + deg(w), rowptr[w+1]) -> col=0, wgt=0
    int w = (idx - 12) * 256 + threadIdx.x;
    if (w >= n) return;
    int p = rowptr[w] + cnt[w];
    int pe = rowptr[w + 1];
    for (; p < pe; p++) {
        col[p] = 0;
        wgt[p] = 0.f;
    }
}

// ---------------- MFMA GEMMs ----------------
// fp32 A (layer 1): hi/lo split, 3 mfma per K-chunk.
template <int NT>
__global__ __launch_bounds__(256) void k_gemm_f32(const float* __restrict__ A,
                                                  const __bf16* __restrict__ Wp_hi,
                                                  const __bf16* __restrict__ Wp_lo,
                                                  __bf16* __restrict__ Cbf, int n) {
    constexpr int N = NT * 16;
    int wave = (int)((blockIdx.x * 256u + threadIdx.x) >> 6);
    int lane = threadIdx.x & 63;
    int row0 = wave * 16;
    if (row0 >= n) return;
    int m = lane & 15;
    int q = lane >> 4;
    int row = row0 + m;
    if (row >= n) row = n - 1;
    const float* ap = A + (size_t)row * 128 + q * 8;
    bf16x8 ahi[4], alo[4];
#pragma unroll
    for (int c = 0; c < 4; c++) {
        float4 v0 = *(const float4*)(ap + c * 32);
        float4 v1 = *(const float4*)(ap + c * 32 + 4);
        float vv[8] = {v0.x, v0.y, v0.z, v0.w, v1.x, v1.y, v1.z, v1.w};
#pragma unroll
        for (int j = 0; j < 8; j++) {
            __bf16 h = (__bf16)vv[j];
            ahi[c][j] = h;
            alo[c][j] = (__bf16)(vv[j] - (float)h);
        }
    }
#pragma unroll
    for (int t = 0; t < NT; t++) {
        f32x4 acc = {0.f, 0.f, 0.f, 0.f};
#pragma unroll
        for (int c = 0; c < 4; c++) {
            size_t off = ((size_t)(t * 4 + c) * 64 + lane) * 8;
            bf16x8 bh = *(const bf16x8*)(Wp_hi + off);
            bf16x8 bl = *(const bf16x8*)(Wp_lo + off);
            acc = __builtin_amdgcn_mfma_f32_16x16x32_bf16(ahi[c], bh, acc, 0, 0, 0);
            acc = __builtin_amdgcn_mfma_f32_16x16x32_bf16(alo[c], bh, acc, 0, 0, 0);
            acc = __builtin_amdgcn_mfma_f32_16x16x32_bf16(ahi[c], bl, acc, 0, 0, 0);
        }
        int colx = t * 16 + m;
#pragma unroll
        for (int r = 0; r < 4; r++) {
            int orow = row0 + q * 4 + r;
            if (orow < n) Cbf[(size_t)orow * N + colx] = (__bf16)acc[r];
        }
    }
}

// bf16 A (layers 2/3): 2 mfma per K-chunk.
template <int NT>
__global__ __launch_bounds__(256) void k_gemm_bf16(const __bf16* __restrict__ A,
                                                   const __bf16* __restrict__ Wp_hi,
                                                   const __bf16* __restrict__ Wp_lo,
                                                   __bf16* __restrict__ Cbf, int n) {
    constexpr int N = NT * 16;
    int wave = (int)((blockIdx.x * 256u + threadIdx.x) >> 6);
    int lane = threadIdx.x & 63;
    int row0 = wave * 16;
    if (row0 >= n) return;
    int m = lane & 15;
    int q = lane >> 4;
    int row = row0 + m;
    if (row >= n) row = n - 1;
    const __bf16* ap = A + (size_t)row * 128 + q * 8;
    bf16x8 a[4];
#pragma unroll
    for (int c = 0; c < 4; c++) a[c] = *(const bf16x8*)(ap + c * 32);
#pragma unroll
    for (int t = 0; t < NT; t++) {
        f32x4 acc = {0.f, 0.f, 0.f, 0.f};
#pragma unroll
        for (int c = 0; c < 4; c++) {
            size_t off = ((size_t)(t * 4 + c) * 64 + lane) * 8;
            bf16x8 bh = *(const bf16x8*)(Wp_hi + off);
            bf16x8 bl = *(const bf16x8*)(Wp_lo + off);
            acc = __builtin_amdgcn_mfma_f32_16x16x32_bf16(a[c], bh, acc, 0, 0, 0);
            acc = __builtin_amdgcn_mfma_f32_16x16x32_bf16(a[c], bl, acc, 0, 0, 0);
        }
        int colx = t * 16 + m;
#pragma unroll
        for (int r = 0; r < 4; r++) {
            int orow = row0 + q * 4 + r;
            if (orow < n) Cbf[(size_t)orow * N + colx] = (__bf16)acc[r];
        }
    }
}

// ---------------- aggregation (padded CSR, 16/8/4-deep gather bursts) ----------------
#define AGG128_BODY(CVEC, WVEC)                                        \
    {                                                                  \
        unsigned u0 = t32[((size_t)CVEC.x << 6) + lane];               \
        unsigned u1 = t32[((size_t)CVEC.y << 6) + lane];               \
        unsigned u2 = t32[((size_t)CVEC.z << 6) + lane];               \
        unsigned u3 = t32[((size_t)CVEC.w << 6) + lane];               \
        a0 += WVEC.x * bflo(u0); a1 += WVEC.x * bfhi(u0);              \
        a0 += WVEC.y * bflo(u1); a1 += WVEC.y * bfhi(u1);              \
        a0 += WVEC.z * bflo(u2); a1 += WVEC.z * bfhi(u2);              \
        a0 += WVEC.w * bflo(u3); a1 += WVEC.w * bfhi(u3);              \
    }

__global__ __launch_bounds__(256) void k_agg128(const unsigned int* __restrict__ t32,
                                                const int* __restrict__ rowptr,
                                                const int* __restrict__ col,
                                                const float* __restrict__ wgt,
                                                const float* __restrict__ dinv,
                                                const float* __restrict__ bias,
                                                unsigned int* __restrict__ out, int n) {
    int w = (int)((blockIdx.x * 256u + threadIdx.x) >> 6);
    int lane = threadIdx.x & 63;
    if (w >= n) return;
    float di = dinv[w];
    float sw = di * di;
    unsigned us = t32[(size_t)w * 64 + lane];
    float a0 = sw * bflo(us);
    float a1 = sw * bfhi(us);
    int p = rowptr[w], pe = rowptr[w + 1];
    for (; p + 16 <= pe; p += 16) {  // 16 gathers in flight
        int4 c0 = *(const int4*)(col + p);
        int4 c1 = *(const int4*)(col + p + 4);
        int4 c2 = *(const int4*)(col + p + 8);
        int4 c3 = *(const int4*)(col + p + 12);
        float4 w0 = *(const float4*)(wgt + p);
        float4 w1 = *(const float4*)(wgt + p + 4);
        float4 w2 = *(const float4*)(wgt + p + 8);
        float4 w3 = *(const float4*)(wgt + p + 12);
        unsigned u0 = t32[((size_t)c0.x << 6) + lane];
        unsigned u1 = t32[((size_t)c0.y << 6) + lane];
        unsigned u2 = t32[((size_t)c0.z << 6) + lane];
        unsigned u3 = t32[((size_t)c0.w << 6) + lane];
        unsigned u4 = t32[((size_t)c1.x << 6) + lane];
        unsigned u5 = t32[((size_t)c1.y << 6) + lane];
        unsigned u6 = t32[((size_t)c1.z << 6) + lane];
        unsigned u7 = t32[((size_t)c1.w << 6) + lane];
        unsigned u8 = t32[((size_t)c2.x << 6) + lane];
        unsigned u9 = t32[((size_t)c2.y << 6) + lane];
        unsigned ua = t32[((size_t)c2.z << 6) + lane];
        unsigned ub = t32[((size_t)c2.w << 6) + lane];
        unsigned uc = t32[((size_t)c3.x << 6) + lane];
        unsigned ud = t32[((size_t)c3.y << 6) + lane];
        unsigned ue = t32[((size_t)c3.z << 6) + lane];
        unsigned uf = t32[((size_t)c3.w << 6) + lane];
        a0 += w0.x * bflo(u0); a1 += w0.x * bfhi(u0);
        a0 += w0.y * bflo(u1); a1 += w0.y * bfhi(u1);
        a0 += w0.z * bflo(u2); a1 += w0.z * bfhi(u2);
        a0 += w0.w * bflo(u3); a1 += w0.w * bfhi(u3);
        a0 += w1.x * bflo(u4); a1 += w1.x * bfhi(u4);
        a0 += w1.y * bflo(u5); a1 += w1.y * bfhi(u5);
        a0 += w1.z * bflo(u6); a1 += w1.z * bfhi(u6);
        a0 += w1.w * bflo(u7); a1 += w1.w * bfhi(u7);
        a0 += w2.x * bflo(u8); a1 += w2.x * bfhi(u8);
        a0 += w2.y * bflo(u9); a1 += w2.y * bfhi(u9);
        a0 += w2.z * bflo(ua); a1 += w2.z * bfhi(ua);
        a0 += w2.w * bflo(ub); a1 += w2.w * bfhi(ub);
        a0 += w3.x * bflo(uc); a1 += w3.x * bfhi(uc);
        a0 += w3.y * bflo(ud); a1 += w3.y * bfhi(ud);
        a0 += w3.z * bflo(ue); a1 += w3.z * bfhi(ue);
        a0 += w3.w * bflo(uf); a1 += w3.w * bfhi(uf);
    }
    for (; p + 8 <= pe; p += 8) {
        int4 c0 = *(const int4*)(col + p);
        int4 c1 = *(const int4*)(col + p + 4);
        float4 w0 = *(const float4*)(wgt + p);
        float4 w1 = *(const float4*)(wgt + p + 4);
        AGG128_BODY(c0, w0)
        AGG128_BODY(c1, w1)
    }
    if (p < pe) {
        int4 c0 = *(const int4*)(col + p);
        float4 w0 = *(const float4*)(wgt + p);
        AGG128_BODY(c0, w0)
    }
    BF2 o;
    o.h[0] = (__bf16)fmaxf(a0 + bias[lane * 2], 0.f);
    o.h[1] = (__bf16)fmaxf(a1 + bias[lane * 2 + 1], 0.f);
    out[(size_t)w * 64 + lane] = o.u;
}

__global__ __launch_bounds__(256) void k_agg64(const unsigned short* __restrict__ t16,
                                               const int* __restrict__ rowptr,
                                               const int* __restrict__ col,
                                               const float* __restrict__ wgt,
                                               const float* __restrict__ dinv,
                                               const float* __restrict__ bias,
                                               __bf16* __restrict__ out, int n) {
    int w = (int)((blockIdx.x * 256u + threadIdx.x) >> 6);
    int lane = threadIdx.x & 63;
    if (w >= n) return;
    float di = dinv[w];
    float sw = di * di;
    float acc = sw * __uint_as_float((unsigned)t16[(size_t)w * 64 + lane] << 16);
    int p = rowptr[w], pe = rowptr[w + 1];
    for (; p + 16 <= pe; p += 16) {
        int4 c0 = *(const int4*)(col + p);
        int4 c1 = *(const int4*)(col + p + 4);
        int4 c2 = *(const int4*)(col + p + 8);
        int4 c3 = *(const int4*)(col + p + 12);
        float4 w0 = *(const float4*)(wgt + p);
        float4 w1 = *(const float4*)(wgt + p + 4);
        float4 w2 = *(const float4*)(wgt + p + 8);
        float4 w3 = *(const float4*)(wgt + p + 12);
        unsigned u0 = t16[((size_t)c0.x << 6) + lane];
        unsigned u1 = t16[((size_t)c0.y << 6) + lane];
        unsigned u2 = t16[((size_t)c0.z << 6) + lane];
        unsigned u3 = t16[((size_t)c0.w << 6) + lane];
        unsigned u4 = t16[((size_t)c1.x << 6) + lane];
        unsigned u5 = t16[((size_t)c1.y << 6) + lane];
        unsigned u6 = t16[((size_t)c1.z << 6) + lane];
        unsigned u7 = t16[((size_t)c1.w << 6) + lane];
        unsigned u8 = t16[((size_t)c2.x << 6) + lane];
        unsigned u9 = t16[((size_t)c2.y << 6) + lane];
        unsigned ua = t16[((size_t)c2.z << 6) + lane];
        unsigned ub = t16[((size_t)c2.w << 6) + lane];
        unsigned uc = t16[((size_t)c3.x << 6) + lane];
        unsigned ud = t16[((size_t)c3.y << 6) + lane];
        unsigned ue = t16[((size_t)c3.z << 6) + lane];
        unsigned uf = t16[((size_t)c3.w << 6) + lane];
        acc += w0.x * __uint_as_float(u0 << 16);
        acc += w0.y * __uint_as_float(u1 << 16);
        acc += w0.z * __uint_as_float(u2 << 16);
        acc += w0.w * __uint_as_float(u3 << 16);
        acc += w1.x * __uint_as_float(u4 << 16);
        acc += w1.y * __uint_as_float(u5 << 16);
        acc += w1.z * __uint_as_float(u6 << 16);
        acc += w1.w * __uint_as_float(u7 << 16);
        acc += w2.x * __uint_as_float(u8 << 16);
        acc += w2.y * __uint_as_float(u9 << 16);
        acc += w2.z * __uint_as_float(ua << 16);
        acc += w2.w * __uint_as_float(ub << 16);
        acc += w3.x * __uint_as_float(uc << 16);
        acc += w3.y * __uint_as_float(ud << 16);
        acc += w3.z * __uint_as_float(ue << 16);
        acc += w3.w * __uint_as_float(uf << 16);
    }
    for (; p + 4 <= pe; p += 4) {
        int4 c0 = *(const int4*)(col + p);
        float4 w0 = *(const float4*)(wgt + p);
        unsigned u0 = t16[((size_t)c0.x << 6) + lane];
        unsigned u1 = t16[((size_t)c0.y << 6) + lane];
        unsigned u2 = t16[((size_t)c0.z << 6) + lane];
        unsigned u3 = t16[((size_t)c0.w << 6) + lane];
        acc += w0.x * __uint_as_float(u0 << 16);
        acc += w0.y * __uint_as_float(u1 << 16);
        acc += w0.z * __uint_as_float(u2 << 16);
        acc += w0.w * __uint_as_float(u3 << 16);
    }
    out[(size_t)w * 64 + lane] = (__bf16)fmaxf(acc + bias[lane], 0.f);
}

// ---------------- fused mean-pool + MLP head ----------------
__global__ __launch_bounds__(256) void k_poolmlp(const unsigned short* __restrict__ h,
                                                 const int* __restrict__ gstart,
                                                 const float* __restrict__ demo,
                                                 const float* __restrict__ Wf1,
                                                 const float* __restrict__ bf1,
                                                 const float* __restrict__ Wf2,
                                                 const float* __restrict__ bf2,
                                                 const float* __restrict__ Wf3,
                                                 const float* __restrict__ bf3,
                                                 float* __restrict__ out, int G) {
    int g = blockIdx.x;
    int tid = threadIdx.x;
    int lane = tid & 63;
    int wv = tid >> 6;
    int s = gstart[g], e = gstart[g + 1];
    float acc = 0.f;
    for (int i = s + wv; i < e; i += 4)
        acc += __uint_as_float((unsigned)h[(size_t)i * 64 + lane] << 16);
    __shared__ float red[4][64];
    __shared__ float zin[72];
    __shared__ float z1[64];
    __shared__ float z2[32];
    red[wv][lane] = acc;
    if (tid >= 64 && tid < 72) zin[tid] = demo[g * 8 + (tid - 64)];
    __syncthreads();
    if (tid < 64) {
        float v = red[0][tid] + red[1][tid] + red[2][tid] + red[3][tid];
        zin[tid] = v / fmaxf((float)(e - s), 1.0f);
    }
    __syncthreads();
    if (tid < 64) {
        float a = bf1[tid];
        for (int k = 0; k < 72; k++) a += zin[k] * Wf1[k * 64 + tid];
        z1[tid] = fmaxf(a, 0.f);
    }
    __syncthreads();
    if (tid < 32) {
        float a2 = bf2[tid];
        for (int k = 0; k < 64; k++) a2 += z1[k] * Wf2[k * 32 + tid];
        z2[tid] = fmaxf(a2, 0.f);
    }
    __syncthreads();
    if (tid < 2) {
        float a3 = bf3[tid];
        for (int k = 0; k < 32; k++) a3 += z2[k] * Wf3[k * 2 + tid];
        out[g * 2 + tid] = a3;
    }
}

extern "C" void kernel_launch(void* const* d_in, const int* in_sizes, int n_in,
                              void* d_out, int out_size, void* d_ws, size_t ws_size,
                              hipStream_t stream) {
    const float* x    = (const float*)d_in[0];
    const int*   ei   = (const int*)d_in[1];
    const int*   batch= (const int*)d_in[2];
    const float* demo = (const float*)d_in[3];
    const float* W1   = (const float*)d_in[4];
    const float* b1   = (const float*)d_in[5];
    const float* W2   = (const float*)d_in[6];
    const float* b2   = (const float*)d_in[7];
    const float* W3   = (const float*)d_in[8];
    const float* b3   = (const float*)d_in[9];
    const float* Wf1  = (const float*)d_in[10];
    const float* bf1  = (const float*)d_in[11];
    const float* Wf2  = (const float*)d_in[12];
    const float* bf2  = (const float*)d_in[13];
    const float* Wf3  = (const float*)d_in[14];
    const float* bf3  = (const float*)d_in[15];
    float* out = (float*)d_out;

    const int n = in_sizes[0] / 128;  // 50000
    const int E = in_sizes[1] / 2;    // 600000
    const int G = in_sizes[3] / 8;    // 100
    const int Epad = E + 3 * n;       // worst-case padded CSR size

    char* ws = (char*)d_ws;
    auto alloc = [&](size_t bytes) {
        char* p = ws;
        ws += (bytes + 255) & ~(size_t)255;
        return p;
    };
    int*    cnt    = (int*)alloc((size_t)n * 4);
    float*  dinv   = (float*)alloc((size_t)n * 4);
    int*    rowptr = (int*)alloc((size_t)(n + 1) * 4);
    int*    fill2  = (int*)alloc((size_t)n * 4);   // scatter cursor (copy of rowptr)
    int*    col    = (int*)alloc((size_t)Epad * 4);
    float*  wgt    = (float*)alloc((size_t)Epad * 4);
    __bf16* tbf    = (__bf16*)alloc((size_t)n * 128 * 2);  // GEMM out bf16 (layers 1/2)
    __bf16* hbuf   = (__bf16*)alloc((size_t)n * 128 * 2);  // agg out bf16
    __bf16* t3bf   = (__bf16*)alloc((size_t)n * 64 * 2);   // GEMM3 out
    __bf16* h3     = (__bf16*)alloc((size_t)n * 64 * 2);   // agg3 out (bf16)
    __bf16* Wp1h   = (__bf16*)alloc(128 * 128 * 2);
    __bf16* Wp1l   = (__bf16*)alloc(128 * 128 * 2);
    __bf16* Wp2h   = (__bf16*)alloc(128 * 128 * 2);
    __bf16* Wp2l   = (__bf16*)alloc(128 * 128 * 2);
    __bf16* Wp3h   = (__bf16*)alloc(128 * 64 * 2);
    __bf16* Wp3l   = (__bf16*)alloc(128 * 64 * 2);
    int*    gstart = (int*)alloc((size_t)(G + 1) * 4);

    const int* srcv = ei;
    const int* dstv = ei + E;

    hipMemsetAsync(cnt, 0, (size_t)n * 4, stream);

    const int EB = (E + 255) / 256;
    const int NB = (n + 255) / 256;
    // k_pre: EB degree blocks + 1 gstart block + 8 wpack(W1) blocks
    k_pre<<<EB + 9, 256, 0, stream>>>(dstv, cnt, batch, gstart, W1, Wp1h, Wp1l, E, n, G, EB);
    k_scan<<<1, 1024, 0, stream>>>(cnt, rowptr, fill2, dinv, n);
    // k_csr: EB scatter blocks + 12 wpack(W2,W3) blocks + NB padding-fill blocks
    k_csr<<<EB + 12 + NB, 256, 0, stream>>>(srcv, dstv, rowptr, fill2, cnt, dinv, col, wgt,
                                            E, EB, n, W2, W3, Wp2h, Wp2l, Wp3h, Wp3l);

    int waves = (n + 15) / 16;
    int gemm_blocks = (waves + 3) / 4;
    int agg_blocks = (int)(((size_t)n * 64 + 255) / 256);

    // Layer 1
    k_gemm_f32<8><<<gemm_blocks, 256, 0, stream>>>(x, Wp1h, Wp1l, tbf, n);
    k_agg128<<<agg_blocks, 256, 0, stream>>>((const unsigned int*)tbf, rowptr, col, wgt,
                                             dinv, b1, (unsigned int*)hbuf, n);
    // Layer 2
    k_gemm_bf16<8><<<gemm_blocks, 256, 0, stream>>>(hbuf, Wp2h, Wp2l, tbf, n);
    k_agg128<<<agg_blocks, 256, 0, stream>>>((const unsigned int*)tbf, rowptr, col, wgt,
                                             dinv, b2, (unsigned int*)hbuf, n);
    // Layer 3 (128 -> 64)
    k_gemm_bf16<4><<<gemm_blocks, 256, 0, stream>>>(hbuf, Wp3h, Wp3l, t3bf, n);
    k_agg64<<<agg_blocks, 256, 0, stream>>>((const unsigned short*)t3bf, rowptr, col, wgt,
                                            dinv, b3, h3, n);

    k_poolmlp<<<G, 256, 0, stream>>>((const unsigned short*)h3, gstart, demo,
                                     Wf1, bf1, Wf2, bf2, Wf3, bf3, out, G);
}

// Round 7
// 339.523 us; speedup vs baseline: 1.4384x; 1.0953x over previous
//
#include <hip/hip_runtime.h>

// ---------------------------------------------------------------------------
// ROIAwareGCN: 3x GCNConv + mean-pool + MLP.
// R1: atomic pool -> segmented reduction over sorted batch.
// R2: split-bf16 MFMA GEMM (no LDS), bf16 t, gather ILP.
// R3: padded CSR (int4/float4, dummy wgt=0), bf16 h, fused preproc.
// R4: pool+mlp fused; pad-fill instead of memset; 16-deep agg bursts; h3 bf16.
// R5: k_scan back to coalesced chunked scan (48us; still top dispatch:
//     13 chunks x 4 barriers, vmcnt(0) drain before every barrier).
// R6: k_scan -> 2-barrier version: Phase A per-chunk wave-scans with totals
//     posted to LDS (no barriers, loads overlap), Phase B single-wave scan of
//     the <=256 (chunk,wave) totals, Phase C coalesced L2-hot reload + write.
// ---------------------------------------------------------------------------

typedef __bf16 bf16x8 __attribute__((ext_vector_type(8)));
typedef float f32x4 __attribute__((ext_vector_type(4)));

__device__ __forceinline__ float bflo(unsigned u) { return __uint_as_float(u << 16); }
__device__ __forceinline__ float bfhi(unsigned u) { return __uint_as_float(u & 0xffff0000u); }

union BF2 {
    __bf16 h[2];
    unsigned u;
};

// ---------------- W pre-pack into MFMA B-fragment layout ----------------
__device__ __forceinline__ void wpack_block(const float* __restrict__ W,
                                            __bf16* __restrict__ hi,
                                            __bf16* __restrict__ lo, int N, int b, int l) {
    int t = b >> 2, c = b & 3;
    int k0 = c * 32 + (l >> 4) * 8;
    int ncol = t * 16 + (l & 15);
    size_t base = ((size_t)b * 64 + l) * 8;
#pragma unroll
    for (int j = 0; j < 8; j++) {
        float v = W[(size_t)(k0 + j) * N + ncol];
        __bf16 h = (__bf16)v;
        hi[base + j] = h;
        lo[base + j] = (__bf16)(v - (float)h);
    }
}

// ---------------- fused: degree count + graph boundaries + wpack(W1) ----------------
__global__ void k_pre(const int* __restrict__ dst, int* __restrict__ cnt,
                      const int* __restrict__ batch, int* __restrict__ gstart,
                      const float* __restrict__ W1, __bf16* __restrict__ Wp1h,
                      __bf16* __restrict__ Wp1l, int E, int n, int G, int EB) {
    int b = blockIdx.x;
    if (b < EB) {
        int e = b * 256 + threadIdx.x;
        if (e < E) atomicAdd(&cnt[dst[e]], 1);
    } else if (b == EB) {
        int g = threadIdx.x;
        if (g <= G) {
            int lo = 0, hi = n;
            while (lo < hi) {
                int mid = (lo + hi) >> 1;
                if (batch[mid] < g) lo = mid + 1; else hi = mid;
            }
            gstart[g] = lo;  // lower_bound: first i with batch[i] >= g
        }
    } else {
        int b64 = (b - EB - 1) * 4 + (threadIdx.x >> 6);  // 0..31
        if (b64 < 32) wpack_block(W1, Wp1h, Wp1l, 128, b64, threadIdx.x & 63);
    }
}

// ---------------- 2-barrier single-block scan -> rowptr, fill2, dinv ----------------
// rowptr over PADDED counts ((c+3)&~3); fill2 = copy of rowptr (scatter cursor).
// Supports n <= 16*4096 = 65536.
__global__ __launch_bounds__(1024) void k_scan(const int* __restrict__ cnt,
                                               int* __restrict__ rowptr,
                                               int* __restrict__ fill2,
                                               float* __restrict__ dinv, int n) {
    __shared__ int lsum[16 * 16];  // [chunk][wave] totals -> exclusive prefixes
    __shared__ int tot_s;
    int tid = threadIdx.x;
    int lane = tid & 63;
    int wid = tid >> 6;
    int chunks = (n + 4095) >> 12;  // <= 16
    int exc[16];

    // Phase A: per-chunk coalesced load, dinv, wave-scan; no barriers.
    for (int c = 0; c < chunks; c++) {
        int i0 = (c << 12) + tid * 4;
        int s = 0;
        if (i0 + 3 < n) {
            int4 v = *(const int4*)(cnt + i0);
            float4 dv;
            dv.x = rsqrtf((float)(v.x + 1));
            dv.y = rsqrtf((float)(v.y + 1));
            dv.z = rsqrtf((float)(v.z + 1));
            dv.w = rsqrtf((float)(v.w + 1));
            *(float4*)(dinv + i0) = dv;
            s = ((v.x + 3) & ~3) + ((v.y + 3) & ~3) + ((v.z + 3) & ~3) + ((v.w + 3) & ~3);
        } else if (i0 < n) {
#pragma unroll
            for (int j = 0; j < 4; j++) {
                if (i0 + j < n) {
                    int v = cnt[i0 + j];
                    dinv[i0 + j] = rsqrtf((float)(v + 1));
                    s += (v + 3) & ~3;
                }
            }
        }
        int sc = s;
#pragma unroll
        for (int d = 1; d < 64; d <<= 1) {
            int o = __shfl_up(sc, d);
            if (lane >= d) sc += o;
        }
        exc[c] = sc - s;  // exclusive prefix within wave
        if (lane == 63) lsum[c * 16 + wid] = sc;
    }
    __syncthreads();

    // Phase B: wave 0 scans chunk-major (chunk,wave) totals (<=256 entries).
    if (wid == 0) {
        int total = chunks * 16;
        int carry = 0;
        for (int base = 0; base < total; base += 64) {
            int idx = base + lane;
            int val = (idx < total) ? lsum[idx] : 0;
            int sc = val;
#pragma unroll
            for (int d = 1; d < 64; d <<= 1) {
                int o = __shfl_up(sc, d);
                if (lane >= d) sc += o;
            }
            int grp = __shfl(sc, 63);
            if (idx < total) lsum[idx] = sc - val + carry;
            carry += grp;
        }
        if (lane == 0) tot_s = carry;
    }
    __syncthreads();

    // Phase C: L2-hot reload, coalesced rowptr/fill2 writes.
    for (int c = 0; c < chunks; c++) {
        int i0 = (c << 12) + tid * 4;
        if (i0 >= n) continue;
        int off = lsum[c * 16 + wid] + exc[c];
        if (i0 + 3 < n) {
            int4 v = *(const int4*)(cnt + i0);
            int o0 = off;
            int o1 = o0 + ((v.x + 3) & ~3);
            int o2 = o1 + ((v.y + 3) & ~3);
            int o3 = o2 + ((v.z + 3) & ~3);
            int4 ov = {o0, o1, o2, o3};
            *(int4*)(rowptr + i0) = ov;
            *(int4*)(fill2 + i0) = ov;
        } else {
            int o = off;
#pragma unroll
            for (int j = 0; j < 4; j++) {
                if (i0 + j < n) {
                    rowptr[i0 + j] = o;
                    fill2[i0 + j] = o;
                    o += (cnt[i0 + j] + 3) & ~3;
                }
            }
        }
    }
    if (tid == 0) rowptr[n] = tot_s;
}

// ---------------- CSR scatter + wpack(W2,W3) + padding fill ----------------
__global__ void k_csr(const int* __restrict__ src, const int* __restrict__ dst,
                      const int* __restrict__ rowptr, int* __restrict__ fill2,
                      const int* __restrict__ cnt,
                      const float* __restrict__ dinv, int* __restrict__ col,
                      float* __restrict__ wgt, int E, int EB, int n,
                      const float* __restrict__ W2, const float* __restrict__ W3,
                      __bf16* __restrict__ Wp2h, __bf16* __restrict__ Wp2l,
                      __bf16* __restrict__ Wp3h, __bf16* __restrict__ Wp3l) {
    int b = blockIdx.x;
    if (b < EB) {
        int e = b * 256 + threadIdx.x;
        if (e >= E) return;
        int s = src[e], d = dst[e];
        int pos = atomicAdd(&fill2[d], 1);
        col[pos] = s;
        wgt[pos] = dinv[s] * dinv[d];
        return;
    }
    int idx = b - EB;
    if (idx < 12) {  // weight packing: 48 wave-blocks
        int b64 = idx * 4 + (threadIdx.x >> 6);
        int l = threadIdx.x & 63;
        if (b64 < 32) wpack_block(W2, Wp2h, Wp2l, 128, b64, l);
        else if (b64 < 48) wpack_block(W3, Wp3h, Wp3l, 64, b64 - 32, l);
        return;
    }
    // padding slots: [rowptr[w] + deg(w), rowptr[w+1]) -> col=0, wgt=0
    int w = (idx - 12) * 256 + threadIdx.x;
    if (w >= n) return;
    int p = rowptr[w] + cnt[w];
    int pe = rowptr[w + 1];
    for (; p < pe; p++) {
        col[p] = 0;
        wgt[p] = 0.f;
    }
}

// ---------------- MFMA GEMMs ----------------
// fp32 A (layer 1): hi/lo split, 3 mfma per K-chunk.
template <int NT>
__global__ __launch_bounds__(256) void k_gemm_f32(const float* __restrict__ A,
                                                  const __bf16* __restrict__ Wp_hi,
                                                  const __bf16* __restrict__ Wp_lo,
                                                  __bf16* __restrict__ Cbf, int n) {
    constexpr int N = NT * 16;
    int wave = (int)((blockIdx.x * 256u + threadIdx.x) >> 6);
    int lane = threadIdx.x & 63;
    int row0 = wave * 16;
    if (row0 >= n) return;
    int m = lane & 15;
    int q = lane >> 4;
    int row = row0 + m;
    if (row >= n) row = n - 1;
    const float* ap = A + (size_t)row * 128 + q * 8;
    bf16x8 ahi[4], alo[4];
#pragma unroll
    for (int c = 0; c < 4; c++) {
        float4 v0 = *(const float4*)(ap + c * 32);
        float4 v1 = *(const float4*)(ap + c * 32 + 4);
        float vv[8] = {v0.x, v0.y, v0.z, v0.w, v1.x, v1.y, v1.z, v1.w};
#pragma unroll
        for (int j = 0; j < 8; j++) {
            __bf16 h = (__bf16)vv[j];
            ahi[c][j] = h;
            alo[c][j] = (__bf16)(vv[j] - (float)h);
        }
    }
#pragma unroll
    for (int t = 0; t < NT; t++) {
        f32x4 acc = {0.f, 0.f, 0.f, 0.f};
#pragma unroll
        for (int c = 0; c < 4; c++) {
            size_t off = ((size_t)(t * 4 + c) * 64 + lane) * 8;
            bf16x8 bh = *(const bf16x8*)(Wp_hi + off);
            bf16x8 bl = *(const bf16x8*)(Wp_lo + off);
            acc = __builtin_amdgcn_mfma_f32_16x16x32_bf16(ahi[c], bh, acc, 0, 0, 0);
            acc = __builtin_amdgcn_mfma_f32_16x16x32_bf16(alo[c], bh, acc, 0, 0, 0);
            acc = __builtin_amdgcn_mfma_f32_16x16x32_bf16(ahi[c], bl, acc, 0, 0, 0);
        }
        int colx = t * 16 + m;
#pragma unroll
        for (int r = 0; r < 4; r++) {
            int orow = row0 + q * 4 + r;
            if (orow < n) Cbf[(size_t)orow * N + colx] = (__bf16)acc[r];
        }
    }
}

// bf16 A (layers 2/3): 2 mfma per K-chunk.
template <int NT>
__global__ __launch_bounds__(256) void k_gemm_bf16(const __bf16* __restrict__ A,
                                                   const __bf16* __restrict__ Wp_hi,
                                                   const __bf16* __restrict__ Wp_lo,
                                                   __bf16* __restrict__ Cbf, int n) {
    constexpr int N = NT * 16;
    int wave = (int)((blockIdx.x * 256u + threadIdx.x) >> 6);
    int lane = threadIdx.x & 63;
    int row0 = wave * 16;
    if (row0 >= n) return;
    int m = lane & 15;
    int q = lane >> 4;
    int row = row0 + m;
    if (row >= n) row = n - 1;
    const __bf16* ap = A + (size_t)row * 128 + q * 8;
    bf16x8 a[4];
#pragma unroll
    for (int c = 0; c < 4; c++) a[c] = *(const bf16x8*)(ap + c * 32);
#pragma unroll
    for (int t = 0; t < NT; t++) {
        f32x4 acc = {0.f, 0.f, 0.f, 0.f};
#pragma unroll
        for (int c = 0; c < 4; c++) {
            size_t off = ((size_t)(t * 4 + c) * 64 + lane) * 8;
            bf16x8 bh = *(const bf16x8*)(Wp_hi + off);
            bf16x8 bl = *(const bf16x8*)(Wp_lo + off);
            acc = __builtin_amdgcn_mfma_f32_16x16x32_bf16(a[c], bh, acc, 0, 0, 0);
            acc = __builtin_amdgcn_mfma_f32_16x16x32_bf16(a[c], bl, acc, 0, 0, 0);
        }
        int colx = t * 16 + m;
#pragma unroll
        for (int r = 0; r < 4; r++) {
            int orow = row0 + q * 4 + r;
            if (orow < n) Cbf[(size_t)orow * N + colx] = (__bf16)acc[r];
        }
    }
}

// ---------------- aggregation (padded CSR, 16/8/4-deep gather bursts) ----------------
#define AGG128_BODY(CVEC, WVEC)                                        \
    {                                                                  \
        unsigned u0 = t32[((size_t)CVEC.x << 6) + lane];               \
        unsigned u1 = t32[((size_t)CVEC.y << 6) + lane];               \
        unsigned u2 = t32[((size_t)CVEC.z << 6) + lane];               \
        unsigned u3 = t32[((size_t)CVEC.w << 6) + lane];               \
        a0 += WVEC.x * bflo(u0); a1 += WVEC.x * bfhi(u0);              \
        a0 += WVEC.y * bflo(u1); a1 += WVEC.y * bfhi(u1);              \
        a0 += WVEC.z * bflo(u2); a1 += WVEC.z * bfhi(u2);              \
        a0 += WVEC.w * bflo(u3); a1 += WVEC.w * bfhi(u3);              \
    }

__global__ __launch_bounds__(256) void k_agg128(const unsigned int* __restrict__ t32,
                                                const int* __restrict__ rowptr,
                                                const int* __restrict__ col,
                                                const float* __restrict__ wgt,
                                                const float* __restrict__ dinv,
                                                const float* __restrict__ bias,
                                                unsigned int* __restrict__ out, int n) {
    int w = (int)((blockIdx.x * 256u + threadIdx.x) >> 6);
    int lane = threadIdx.x & 63;
    if (w >= n) return;
    float di = dinv[w];
    float sw = di * di;
    unsigned us = t32[(size_t)w * 64 + lane];
    float a0 = sw * bflo(us);
    float a1 = sw * bfhi(us);
    int p = rowptr[w], pe = rowptr[w + 1];
    for (; p + 16 <= pe; p += 16) {  // 16 gathers in flight
        int4 c0 = *(const int4*)(col + p);
        int4 c1 = *(const int4*)(col + p + 4);
        int4 c2 = *(const int4*)(col + p + 8);
        int4 c3 = *(const int4*)(col + p + 12);
        float4 w0 = *(const float4*)(wgt + p);
        float4 w1 = *(const float4*)(wgt + p + 4);
        float4 w2 = *(const float4*)(wgt + p + 8);
        float4 w3 = *(const float4*)(wgt + p + 12);
        unsigned u0 = t32[((size_t)c0.x << 6) + lane];
        unsigned u1 = t32[((size_t)c0.y << 6) + lane];
        unsigned u2 = t32[((size_t)c0.z << 6) + lane];
        unsigned u3 = t32[((size_t)c0.w << 6) + lane];
        unsigned u4 = t32[((size_t)c1.x << 6) + lane];
        unsigned u5 = t32[((size_t)c1.y << 6) + lane];
        unsigned u6 = t32[((size_t)c1.z << 6) + lane];
        unsigned u7 = t32[((size_t)c1.w << 6) + lane];
        unsigned u8 = t32[((size_t)c2.x << 6) + lane];
        unsigned u9 = t32[((size_t)c2.y << 6) + lane];
        unsigned ua = t32[((size_t)c2.z << 6) + lane];
        unsigned ub = t32[((size_t)c2.w << 6) + lane];
        unsigned uc = t32[((size_t)c3.x << 6) + lane];
        unsigned ud = t32[((size_t)c3.y << 6) + lane];
        unsigned ue = t32[((size_t)c3.z << 6) + lane];
        unsigned uf = t32[((size_t)c3.w << 6) + lane];
        a0 += w0.x * bflo(u0); a1 += w0.x * bfhi(u0);
        a0 += w0.y * bflo(u1); a1 += w0.y * bfhi(u1);
        a0 += w0.z * bflo(u2); a1 += w0.z * bfhi(u2);
        a0 += w0.w * bflo(u3); a1 += w0.w * bfhi(u3);
        a0 += w1.x * bflo(u4); a1 += w1.x * bfhi(u4);
        a0 += w1.y * bflo(u5); a1 += w1.y * bfhi(u5);
        a0 += w1.z * bflo(u6); a1 += w1.z * bfhi(u6);
        a0 += w1.w * bflo(u7); a1 += w1.w * bfhi(u7);
        a0 += w2.x * bflo(u8); a1 += w2.x * bfhi(u8);
        a0 += w2.y * bflo(u9); a1 += w2.y * bfhi(u9);
        a0 += w2.z * bflo(ua); a1 += w2.z * bfhi(ua);
        a0 += w2.w * bflo(ub); a1 += w2.w * bfhi(ub);
        a0 += w3.x * bflo(uc); a1 += w3.x * bfhi(uc);
        a0 += w3.y * bflo(ud); a1 += w3.y * bfhi(ud);
        a0 += w3.z * bflo(ue); a1 += w3.z * bfhi(ue);
        a0 += w3.w * bflo(uf); a1 += w3.w * bfhi(uf);
    }
    for (; p + 8 <= pe; p += 8) {
        int4 c0 = *(const int4*)(col + p);
        int4 c1 = *(const int4*)(col + p + 4);
        float4 w0 = *(const float4*)(wgt + p);
        float4 w1 = *(const float4*)(wgt + p + 4);
        AGG128_BODY(c0, w0)
        AGG128_BODY(c1, w1)
    }
    if (p < pe) {
        int4 c0 = *(const int4*)(col + p);
        float4 w0 = *(const float4*)(wgt + p);
        AGG128_BODY(c0, w0)
    }
    BF2 o;
    o.h[0] = (__bf16)fmaxf(a0 + bias[lane * 2], 0.f);
    o.h[1] = (__bf16)fmaxf(a1 + bias[lane * 2 + 1], 0.f);
    out[(size_t)w * 64 + lane] = o.u;
}

__global__ __launch_bounds__(256) void k_agg64(const unsigned short* __restrict__ t16,
                                               const int* __restrict__ rowptr,
                                               const int* __restrict__ col,
                                               const float* __restrict__ wgt,
                                               const float* __restrict__ dinv,
                                               const float* __restrict__ bias,
                                               __bf16* __restrict__ out, int n) {
    int w = (int)((blockIdx.x * 256u + threadIdx.x) >> 6);
    int lane = threadIdx.x & 63;
    if (w >= n) return;
    float di = dinv[w];
    float sw = di * di;
    float acc = sw * __uint_as_float((unsigned)t16[(size_t)w * 64 + lane] << 16);
    int p = rowptr[w], pe = rowptr[w + 1];
    for (; p + 16 <= pe; p += 16) {
        int4 c0 = *(const int4*)(col + p);
        int4 c1 = *(const int4*)(col + p + 4);
        int4 c2 = *(const int4*)(col + p + 8);
        int4 c3 = *(const int4*)(col + p + 12);
        float4 w0 = *(const float4*)(wgt + p);
        float4 w1 = *(const float4*)(wgt + p + 4);
        float4 w2 = *(const float4*)(wgt + p + 8);
        float4 w3 = *(const float4*)(wgt + p + 12);
        unsigned u0 = t16[((size_t)c0.x << 6) + lane];
        unsigned u1 = t16[((size_t)c0.y << 6) + lane];
        unsigned u2 = t16[((size_t)c0.z << 6) + lane];
        unsigned u3 = t16[((size_t)c0.w << 6) + lane];
        unsigned u4 = t16[((size_t)c1.x << 6) + lane];
        unsigned u5 = t16[((size_t)c1.y << 6) + lane];
        unsigned u6 = t16[((size_t)c1.z << 6) + lane];
        unsigned u7 = t16[((size_t)c1.w << 6) + lane];
        unsigned u8 = t16[((size_t)c2.x << 6) + lane];
        unsigned u9 = t16[((size_t)c2.y << 6) + lane];
        unsigned ua = t16[((size_t)c2.z << 6) + lane];
        unsigned ub = t16[((size_t)c2.w << 6) + lane];
        unsigned uc = t16[((size_t)c3.x << 6) + lane];
        unsigned ud = t16[((size_t)c3.y << 6) + lane];
        unsigned ue = t16[((size_t)c3.z << 6) + lane];
        unsigned uf = t16[((size_t)c3.w << 6) + lane];
        acc += w0.x * __uint_as_float(u0 << 16);
        acc += w0.y * __uint_as_float(u1 << 16);
        acc += w0.z * __uint_as_float(u2 << 16);
        acc += w0.w * __uint_as_float(u3 << 16);
        acc += w1.x * __uint_as_float(u4 << 16);
        acc += w1.y * __uint_as_float(u5 << 16);
        acc += w1.z * __uint_as_float(u6 << 16);
        acc += w1.w * __uint_as_float(u7 << 16);
        acc += w2.x * __uint_as_float(u8 << 16);
        acc += w2.y * __uint_as_float(u9 << 16);
        acc += w2.z * __uint_as_float(ua << 16);
        acc += w2.w * __uint_as_float(ub << 16);
        acc += w3.x * __uint_as_float(uc << 16);
        acc += w3.y * __uint_as_float(ud << 16);
        acc += w3.z * __uint_as_float(ue << 16);
        acc += w3.w * __uint_as_float(uf << 16);
    }
    for (; p + 4 <= pe; p += 4) {
        int4 c0 = *(const int4*)(col + p);
        float4 w0 = *(const float4*)(wgt + p);
        unsigned u0 = t16[((size_t)c0.x << 6) + lane];
        unsigned u1 = t16[((size_t)c0.y << 6) + lane];
        unsigned u2 = t16[((size_t)c0.z << 6) + lane];
        unsigned u3 = t16[((size_t)c0.w << 6) + lane];
        acc += w0.x * __uint_as_float(u0 << 16);
        acc += w0.y * __uint_as_float(u1 << 16);
        acc += w0.z * __uint_as_float(u2 << 16);
        acc += w0.w * __uint_as_float(u3 << 16);
    }
    out[(size_t)w * 64 + lane] = (__bf16)fmaxf(acc + bias[lane], 0.f);
}

// ---------------- fused mean-pool + MLP head ----------------
__global__ __launch_bounds__(256) void k_poolmlp(const unsigned short* __restrict__ h,
                                                 const int* __restrict__ gstart,
                                                 const float* __restrict__ demo,
                                                 const float* __restrict__ Wf1,
                                                 const float* __restrict__ bf1,
                                                 const float* __restrict__ Wf2,
                                                 const float* __restrict__ bf2,
                                                 const float* __restrict__ Wf3,
                                                 const float* __restrict__ bf3,
                                                 float* __restrict__ out, int G) {
    int g = blockIdx.x;
    int tid = threadIdx.x;
    int lane = tid & 63;
    int wv = tid >> 6;
    int s = gstart[g], e = gstart[g + 1];
    float acc = 0.f;
    for (int i = s + wv; i < e; i += 4)
        acc += __uint_as_float((unsigned)h[(size_t)i * 64 + lane] << 16);
    __shared__ float red[4][64];
    __shared__ float zin[72];
    __shared__ float z1[64];
    __shared__ float z2[32];
    red[wv][lane] = acc;
    if (tid >= 64 && tid < 72) zin[tid] = demo[g * 8 + (tid - 64)];
    __syncthreads();
    if (tid < 64) {
        float v = red[0][tid] + red[1][tid] + red[2][tid] + red[3][tid];
        zin[tid] = v / fmaxf((float)(e - s), 1.0f);
    }
    __syncthreads();
    if (tid < 64) {
        float a = bf1[tid];
        for (int k = 0; k < 72; k++) a += zin[k] * Wf1[k * 64 + tid];
        z1[tid] = fmaxf(a, 0.f);
    }
    __syncthreads();
    if (tid < 32) {
        float a2 = bf2[tid];
        for (int k = 0; k < 64; k++) a2 += z1[k] * Wf2[k * 32 + tid];
        z2[tid] = fmaxf(a2, 0.f);
    }
    __syncthreads();
    if (tid < 2) {
        float a3 = bf3[tid];
        for (int k = 0; k < 32; k++) a3 += z2[k] * Wf3[k * 2 + tid];
        out[g * 2 + tid] = a3;
    }
}

extern "C" void kernel_launch(void* const* d_in, const int* in_sizes, int n_in,
                              void* d_out, int out_size, void* d_ws, size_t ws_size,
                              hipStream_t stream) {
    const float* x    = (const float*)d_in[0];
    const int*   ei   = (const int*)d_in[1];
    const int*   batch= (const int*)d_in[2];
    const float* demo = (const float*)d_in[3];
    const float* W1   = (const float*)d_in[4];
    const float* b1   = (const float*)d_in[5];
    const float* W2   = (const float*)d_in[6];
    const float* b2   = (const float*)d_in[7];
    const float* W3   = (const float*)d_in[8];
    const float* b3   = (const float*)d_in[9];
    const float* Wf1  = (const float*)d_in[10];
    const float* bf1  = (const float*)d_in[11];
    const float* Wf2  = (const float*)d_in[12];
    const float* bf2  = (const float*)d_in[13];
    const float* Wf3  = (const float*)d_in[14];
    const float* bf3  = (const float*)d_in[15];
    float* out = (float*)d_out;

    const int n = in_sizes[0] / 128;  // 50000
    const int E = in_sizes[1] / 2;    // 600000
    const int G = in_sizes[3] / 8;    // 100
    const int Epad = E + 3 * n;       // worst-case padded CSR size

    char* ws = (char*)d_ws;
    auto alloc = [&](size_t bytes) {
        char* p = ws;
        ws += (bytes + 255) & ~(size_t)255;
        return p;
    };
    int*    cnt    = (int*)alloc((size_t)n * 4);
    float*  dinv   = (float*)alloc((size_t)n * 4);
    int*    rowptr = (int*)alloc((size_t)(n + 1) * 4);
    int*    fill2  = (int*)alloc((size_t)n * 4);   // scatter cursor (copy of rowptr)
    int*    col    = (int*)alloc((size_t)Epad * 4);
    float*  wgt    = (float*)alloc((size_t)Epad * 4);
    __bf16* tbf    = (__bf16*)alloc((size_t)n * 128 * 2);  // GEMM out bf16 (layers 1/2)
    __bf16* hbuf   = (__bf16*)alloc((size_t)n * 128 * 2);  // agg out bf16
    __bf16* t3bf   = (__bf16*)alloc((size_t)n * 64 * 2);   // GEMM3 out
    __bf16* h3     = (__bf16*)alloc((size_t)n * 64 * 2);   // agg3 out (bf16)
    __bf16* Wp1h   = (__bf16*)alloc(128 * 128 * 2);
    __bf16* Wp1l   = (__bf16*)alloc(128 * 128 * 2);
    __bf16* Wp2h   = (__bf16*)alloc(128 * 128 * 2);
    __bf16* Wp2l   = (__bf16*)alloc(128 * 128 * 2);
    __bf16* Wp3h   = (__bf16*)alloc(128 * 64 * 2);
    __bf16* Wp3l   = (__bf16*)alloc(128 * 64 * 2);
    int*    gstart = (int*)alloc((size_t)(G + 1) * 4);

    const int* srcv = ei;
    const int* dstv = ei + E;

    hipMemsetAsync(cnt, 0, (size_t)n * 4, stream);

    const int EB = (E + 255) / 256;
    const int NB = (n + 255) / 256;
    // k_pre: EB degree blocks + 1 gstart block + 8 wpack(W1) blocks
    k_pre<<<EB + 9, 256, 0, stream>>>(dstv, cnt, batch, gstart, W1, Wp1h, Wp1l, E, n, G, EB);
    k_scan<<<1, 1024, 0, stream>>>(cnt, rowptr, fill2, dinv, n);
    // k_csr: EB scatter blocks + 12 wpack(W2,W3) blocks + NB padding-fill blocks
    k_csr<<<EB + 12 + NB, 256, 0, stream>>>(srcv, dstv, rowptr, fill2, cnt, dinv, col, wgt,
                                            E, EB, n, W2, W3, Wp2h, Wp2l, Wp3h, Wp3l);

    int waves = (n + 15) / 16;
    int gemm_blocks = (waves + 3) / 4;
    int agg_blocks = (int)(((size_t)n * 64 + 255) / 256);

    // Layer 1
    k_gemm_f32<8><<<gemm_blocks, 256, 0, stream>>>(x, Wp1h, Wp1l, tbf, n);
    k_agg128<<<agg_blocks, 256, 0, stream>>>((const unsigned int*)tbf, rowptr, col, wgt,
                                             dinv, b1, (unsigned int*)hbuf, n);
    // Layer 2
    k_gemm_bf16<8><<<gemm_blocks, 256, 0, stream>>>(hbuf, Wp2h, Wp2l, tbf, n);
    k_agg128<<<agg_blocks, 256, 0, stream>>>((const unsigned int*)tbf, rowptr, col, wgt,
                                             dinv, b2, (unsigned int*)hbuf, n);
    // Layer 3 (128 -> 64)
    k_gemm_bf16<4><<<gemm_blocks, 256, 0, stream>>>(hbuf, Wp3h, Wp3l, t3bf, n);
    k_agg64<<<agg_blocks, 256, 0, stream>>>((const unsigned short*)t3bf, rowptr, col, wgt,
                                            dinv, b3, h3, n);

    k_poolmlp<<<G, 256, 0, stream>>>((const unsigned short*)h3, gstart, demo,
                                     Wf1, bf1, Wf2, bf2, Wf3, bf3, out, G);
}